// Round 1
// baseline (35.508 us; speedup 1.0000x reference)
//
#include <hip/hip_runtime.h>
#include <hip/hip_bf16.h>

// Subpixel / pixel-shuffle, r=2:
//   out[n, 2i+r2, 2j+r1, q] = x[n, i, j, q*4 + r1*2 + r2]
// x: (32, 256, 256, 12) fp32  ->  out: (32, 512, 512, 3) fp32
//
// One thread per input pixel (n,i,j): read 12 contiguous floats (3x float4),
// scatter 6 floats to each of output rows 2i and 2i+1 as 3x float2 stores.

#define B  32
#define H  256
#define W  256
#define C  12
#define Q  3
#define OW (W * 2)   // 512

__global__ __launch_bounds__(256) void subpixel_kernel(const float* __restrict__ x,
                                                       float* __restrict__ out) {
    const int idx = blockIdx.x * blockDim.x + threadIdx.x;  // 0 .. B*H*W-1
    const int j = idx & (W - 1);
    const int i = (idx >> 8) & (H - 1);
    const int n = idx >> 16;

    const float4* __restrict__ inp = reinterpret_cast<const float4*>(x + (size_t)idx * C);
    const float4 v0 = inp[0];  // c0..c3  : q=0, (r1,r2) = (0,0),(0,1),(1,0),(1,1)
    const float4 v1 = inp[1];  // c4..c7  : q=1
    const float4 v2 = inp[2];  // c8..c11 : q=2

    // output row base for oi = 2i, columns start at oj = 2j, Q=3 channels
    float* __restrict__ o0 = out + ((size_t)((n * (H * 2) + 2 * i) * OW + 2 * j)) * Q;
    float* __restrict__ o1 = o0 + (size_t)OW * Q;  // row oi = 2i+1

    // row 2i   (r2=0): [c0, c4, c8,  c2, c6, c10]
    // row 2i+1 (r2=1): [c1, c5, c9,  c3, c7, c11]
    float2* __restrict__ s0 = reinterpret_cast<float2*>(o0);
    float2* __restrict__ s1 = reinterpret_cast<float2*>(o1);
    s0[0] = make_float2(v0.x, v1.x);
    s0[1] = make_float2(v2.x, v0.z);
    s0[2] = make_float2(v1.z, v2.z);
    s1[0] = make_float2(v0.y, v1.y);
    s1[1] = make_float2(v2.y, v0.w);
    s1[2] = make_float2(v1.w, v2.w);
}

extern "C" void kernel_launch(void* const* d_in, const int* in_sizes, int n_in,
                              void* d_out, int out_size, void* d_ws, size_t ws_size,
                              hipStream_t stream) {
    const float* x = (const float*)d_in[0];
    float* out = (float*)d_out;

    const int n_pix = B * H * W;             // 2,097,152
    const int block = 256;
    const int grid = n_pix / block;          // 8192
    subpixel_kernel<<<grid, block, 0, stream>>>(x, out);
}